// Round 9
// baseline (1176.932 us; speedup 1.0000x reference)
//
#include <hip/hip_runtime.h>

#define EPS 1e-5f
#define PROJ_EPS 1e-5f
#define MAX_TANH_ARG 15.0f

typedef __bf16 bf16x8 __attribute__((ext_vector_type(8)));
typedef float f32x4 __attribute__((ext_vector_type(4)));
typedef float f32x2 __attribute__((ext_vector_type(2)));

__device__ __forceinline__ unsigned short f2bf(float f) {
  unsigned u = __builtin_bit_cast(unsigned, f);
  u += 0x7fffu + ((u >> 16) & 1u);   // round-to-nearest-even
  return (unsigned short)(u >> 16);
}

union BF8 {
  unsigned short u[8];
  bf16x8 v;
  uint4 q;
};

// ---------------------------------------------------------------------------
// prep: (a) W -> bf16 MFMA B-frag order; (b) edges u16 id | f16 w; (c) zero
// the per-tile completion flags (ws is poisoned 0xAA before every launch).
// ---------------------------------------------------------------------------
__global__ __launch_bounds__(256) void prep_kernel(
    const float* __restrict__ W, const int* __restrict__ adj,
    const float* __restrict__ wgt, unsigned short* __restrict__ wpack,
    unsigned* __restrict__ edges, int* __restrict__ flags,
    int nedge, int nflags) {
  const int tid = blockIdx.x * 256 + threadIdx.x;
  if (tid < nflags) flags[tid] = 0;
  if (tid < 4096) {
    const int l = tid & 63;
    const int s = (tid >> 6) & 3;
    const int tt = (tid >> 8) & 7;
    const int layer = tid >> 11;
    const int q2 = l >> 4;
    const int n = tt * 16 + (l & 15);
    unsigned short* dst = wpack + ((size_t)((layer * 32 + tt * 4 + s) * 64 + l)) * 8;
    const float* src = W + (size_t)layer * 16384;
#pragma unroll
    for (int j = 0; j < 8; ++j) {
      const int k = s * 32 + q2 * 8 + j;
      dst[j] = f2bf(src[(size_t)k * 128 + n]);
    }
  }
  const int e = tid - 4096;
  if (e >= 0 && e < nedge) {
    const unsigned id = (unsigned)adj[e] & 0xffffu;
    const unsigned short h = __builtin_bit_cast(unsigned short, (_Float16)wgt[e]);
    edges[e] = id | ((unsigned)h << 16);
  }
}

// ---------------------------------------------------------------------------
// gemm0: msg1 planes = mask^2 * (node_repr @ W0). Wave-local LDS A/C tile.
// ---------------------------------------------------------------------------
__global__ __launch_bounds__(256) void gemm0_kernel(
    const float* __restrict__ xf, const float* __restrict__ mask,
    const unsigned short* __restrict__ wpack, unsigned short* __restrict__ msg,
    int N, int planeBytes) {
  __shared__ unsigned short tile[64][136];
  const int lane = threadIdx.x & 63;
  const int wv = threadIdx.x >> 6;
  const int m = lane & 15;
  const int quad = lane >> 4;
  const int wbase = blockIdx.x * 64 + wv * 16;

  {
    const int r = lane >> 2;
    const int c = (lane & 3) * 32;
    const int gr = wbase + r;
    const int grc = gr < N ? gr : N - 1;
    const float4* src = (const float4*)(xf + (size_t)grc * 128 + c);
    unsigned short* drow = &tile[wv * 16 + r][c];
#pragma unroll
    for (int i = 0; i < 8; ++i) {
      const float4 p = src[i];
      drow[i * 4 + 0] = f2bf(p.x);
      drow[i * 4 + 1] = f2bf(p.y);
      drow[i * 4 + 2] = f2bf(p.z);
      drow[i * 4 + 3] = f2bf(p.w);
    }
  }

  f32x4 acc[8];
#pragma unroll
  for (int tt = 0; tt < 8; ++tt) acc[tt] = (f32x4){0.f, 0.f, 0.f, 0.f};
#pragma unroll
  for (int sk = 0; sk < 4; ++sk) {
    BF8 a;
    a.q = *(const uint4*)&tile[wv * 16 + m][sk * 32 + quad * 8];
#pragma unroll
    for (int tt = 0; tt < 8; ++tt) {
      BF8 b;
      b.q = *(const uint4*)(wpack + (size_t)((tt * 4 + sk) * 64 + lane) * 8);
      acc[tt] = __builtin_amdgcn_mfma_f32_16x16x32_bf16(a.v, b.v, acc[tt], 0, 0, 0);
    }
  }

  float sc[4];
#pragma unroll
  for (int r = 0; r < 4; ++r) {
    int rr = wbase + quad * 4 + r;
    rr = rr < N ? rr : N - 1;
    const float s = mask[rr];
    sc[r] = s * s;
  }
#pragma unroll
  for (int tt = 0; tt < 8; ++tt) {
    const int c = tt * 16 + m;
#pragma unroll
    for (int r = 0; r < 4; ++r)
      tile[wv * 16 + quad * 4 + r][c] = f2bf(acc[tt][r] * sc[r]);
  }
  const int r16 = lane >> 2;
  const int sub2 = lane & 3;
  const int grow = wbase + r16;
  if (grow < N) {
#pragma unroll
    for (int p = 0; p < 4; ++p) {
      *(uint4*)((char*)msg + (size_t)p * planeBytes + (size_t)grow * 64 + sub2 * 16) =
          *(const uint4*)((const char*)&tile[wv * 16 + r16][0] + p * 64 + sub2 * 16);
    }
  }
}

// ---------------------------------------------------------------------------
// gather + tail: block = (tile = bid>>2, plane = bid&3), XCD-affine planes,
// 8-deep pipelined uint4 gathers. After storing relu(c) plane + partials,
// release-fence + atomicAdd(tileflag); the 4th arriver acquire-fences and
// runs the consumer for the whole tile (split-K-semaphore pattern):
//   LAYER 0: gemm1  -> msg2 planes (cA/scalA are cache-hot)
//   LAYER 1: final  -> fp32 out
// ---------------------------------------------------------------------------
template <int LAYER>
__global__ __launch_bounds__(256, 4) void gather_tail_kernel(
    const unsigned short* __restrict__ msg, const unsigned* __restrict__ edges,
    unsigned short* __restrict__ cout, float* __restrict__ scal,
    const float* __restrict__ mask, const unsigned short* __restrict__ wpack2,
    unsigned short* __restrict__ msgOut, float* __restrict__ out,
    int* __restrict__ flags, int N, int planeBytes) {
  __shared__ union {
    unsigned ep[64 * 36];
    unsigned short tile[64][136];
  } sm;
  __shared__ int lastv;
  const int t = threadIdx.x;
  const int p = blockIdx.x & 3;
  const int tb = blockIdx.x >> 2;
  const int nbase = tb * 64;

  for (int e = t; e < 64 * 32; e += 256) {
    const int node = e >> 5, k = e & 31;
    const int gn = nbase + node;
    sm.ep[node * 36 + k] = (gn < N) ? edges[(size_t)gn * 32 + k] : 0u;
  }
  __syncthreads();

  const int node = t >> 2;
  const int sub = t & 3;
  const int gnode = nbase + node;
  const unsigned* mp = sm.ep + node * 36;
  const char* plane = (const char*)msg + (size_t)p * planeBytes;
  const int suboff = sub * 16;

  unsigned ew[32];
#pragma unroll
  for (int i = 0; i < 8; ++i)
    *(uint4*)&ew[4 * i] = *(const uint4*)(mp + 4 * i);

  f32x2 acc[4];
#pragma unroll
  for (int d = 0; d < 4; ++d) acc[d] = (f32x2){0.f, 0.f};

  uint4 q[8], q2[8];
#pragma unroll
  for (int k = 0; k < 8; ++k)
    q[k] = *(const uint4*)(plane + ((size_t)(ew[k] & 0xffffu) * 64 + suboff));

#pragma unroll
  for (int b = 0; b < 4; ++b) {
    if (b < 3) {
#pragma unroll
      for (int k = 0; k < 8; ++k)
        q2[k] = *(const uint4*)(plane +
                                ((size_t)(ew[8 * (b + 1) + k] & 0xffffu) * 64 + suboff));
    }
#pragma unroll
    for (int k = 0; k < 8; ++k) {
      const float w = (float)__builtin_bit_cast(
          _Float16, (unsigned short)(ew[8 * b + k] >> 16));
      const f32x2 w2 = {w, w};
#pragma unroll
      for (int d = 0; d < 4; ++d) {
        const unsigned qd = (&q[k].x)[d];
        f32x2 v2;
        v2.x = __builtin_bit_cast(float, qd << 16);
        v2.y = __builtin_bit_cast(float, qd & 0xffff0000u);
        acc[d] = __builtin_elementwise_fma(v2, w2, acc[d]);
      }
    }
    if (b < 3) {
#pragma unroll
      for (int k = 0; k < 8; ++k) q[k] = q2[k];
    }
  }

  float s_all = 0.f, s_rel = 0.f;
  uint4 pk4;
  unsigned* pw = &pk4.x;
#pragma unroll
  for (int d = 0; d < 4; ++d) {
    s_all = fmaf(acc[d].x, acc[d].x, s_all);
    s_all = fmaf(acc[d].y, acc[d].y, s_all);
    const float r0 = fmaxf(acc[d].x, 0.f);
    const float r1 = fmaxf(acc[d].y, 0.f);
    s_rel = fmaf(r0, r0, s_rel);
    s_rel = fmaf(r1, r1, s_rel);
    pw[d] = (unsigned)f2bf(r0) | ((unsigned)f2bf(r1) << 16);
  }
  s_all += __shfl_xor(s_all, 1);
  s_all += __shfl_xor(s_all, 2);
  s_rel += __shfl_xor(s_rel, 1);
  s_rel += __shfl_xor(s_rel, 2);

  if (gnode < N) {
    *(uint4*)((char*)cout + (size_t)p * planeBytes + (size_t)gnode * 64 + suboff) = pk4;
    if (sub == 0)
      *(float2*)(scal + (size_t)gnode * 8 + p * 2) = make_float2(s_all, s_rel);
  }

  // ---- completion protocol: 4th arriver consumes the tile ----
  __syncthreads();  // all block stores issued & drained (waitcnt before barrier)
  if (t == 0) {
    __threadfence();  // agent release: write back this XCD's dirty L2 lines
    const int old = __hip_atomic_fetch_add(&flags[tb], 1, __ATOMIC_RELAXED,
                                           __HIP_MEMORY_SCOPE_AGENT);
    lastv = (old == 3);
  }
  __syncthreads();
  if (!lastv) return;
  __threadfence();  // agent acquire: invalidate stale L1/L2 before peer reads
  __syncthreads();  // ep dead; sm.tile may be overwritten below

  const int lane = t & 63;
  const int wv = t >> 6;

  if (LAYER == 0) {
    // ---- gemm1 tail: msg2 planes = rs * (relu(c1) @ W1) for this tile ----
    const int m = lane & 15;
    const int quad = lane >> 4;
    const int wbase = nbase + wv * 16;
    const int row = wbase + m;
    const int rowc = row < N ? row : N - 1;

    f32x4 accg[8];
#pragma unroll
    for (int tt = 0; tt < 8; ++tt) accg[tt] = (f32x4){0.f, 0.f, 0.f, 0.f};
#pragma unroll
    for (int sk = 0; sk < 4; ++sk) {
      BF8 a;
      a.q = *(const uint4*)((const char*)cout + (size_t)sk * planeBytes +
                            (size_t)rowc * 64 + quad * 16);
#pragma unroll
      for (int tt = 0; tt < 8; ++tt) {
        BF8 b;
        b.q = *(const uint4*)(wpack2 + (size_t)((tt * 4 + sk) * 64 + lane) * 8);
        accg[tt] = __builtin_amdgcn_mfma_f32_16x16x32_bf16(a.v, b.v, accg[tt], 0, 0, 0);
      }
    }
    float sc[4];
#pragma unroll
    for (int r = 0; r < 4; ++r) {
      int rr = wbase + quad * 4 + r;
      rr = rr < N ? rr : N - 1;
      const float* s8 = scal + (size_t)rr * 8;
      const float S_all = s8[0] + s8[2] + s8[4] + s8[6];
      const float S_rel = s8[1] + s8[3] + s8[5] + s8[7];
      const float mm = mask[rr];
      const float s2 = mm * mm * S_all;
      const float nrm = sqrtf(s2);
      const float ncl = fminf(fmaxf(nrm, EPS), MAX_TANH_ARG);
      const float f1 = tanhf(ncl) / fmaxf(nrm, EPS) * mm * mm * mm;
      const float r2 = f1 * f1 * S_rel;
      const float nr = sqrtf(r2);
      const float nc2 = fminf(fmaxf(nr, EPS), 1.0f - PROJ_EPS);
      const float ls = 0.5f * logf((1.f + nc2) / (1.f - nc2)) / fmaxf(nr, EPS);
      sc[r] = ls * mm * mm * f1;
    }
#pragma unroll
    for (int tt = 0; tt < 8; ++tt) {
      const int c = tt * 16 + m;
#pragma unroll
      for (int r = 0; r < 4; ++r)
        sm.tile[wv * 16 + quad * 4 + r][c] = f2bf(accg[tt][r] * sc[r]);
    }
    const int r16 = lane >> 2;
    const int sub2 = lane & 3;
    const int grow = nbase + wv * 16 + r16;
    if (grow < N) {
#pragma unroll
      for (int pp = 0; pp < 4; ++pp) {
        *(uint4*)((char*)msgOut + (size_t)pp * planeBytes + (size_t)grow * 64 + sub2 * 16) =
            *(const uint4*)((const char*)&sm.tile[wv * 16 + r16][0] + pp * 64 + sub2 * 16);
      }
    }
  } else {
    // ---- final tail: out = f2 * relu(c2) for this tile, fp32 ----
    if (gnode < N) {
      const float* s8 = scal + (size_t)gnode * 8;
      const float S_all = s8[0] + s8[2] + s8[4] + s8[6];
      const float mm = mask[gnode];
      const float s2 = mm * mm * S_all;
      const float nrm = sqrtf(s2);
      const float ncl = fminf(fmaxf(nrm, EPS), MAX_TANH_ARG);
      const float f2 = tanhf(ncl) / fmaxf(nrm, EPS) * mm * mm * mm;
#pragma unroll
      for (int pp = 0; pp < 4; ++pp) {
        const uint4 qq = *(const uint4*)((const char*)cout + (size_t)pp * planeBytes +
                                         (size_t)gnode * 64 + sub * 16);
        float4 o0, o1;
        o0.x = f2 * __builtin_bit_cast(float, qq.x << 16);
        o0.y = f2 * __builtin_bit_cast(float, qq.x & 0xffff0000u);
        o0.z = f2 * __builtin_bit_cast(float, qq.y << 16);
        o0.w = f2 * __builtin_bit_cast(float, qq.y & 0xffff0000u);
        o1.x = f2 * __builtin_bit_cast(float, qq.z << 16);
        o1.y = f2 * __builtin_bit_cast(float, qq.z & 0xffff0000u);
        o1.z = f2 * __builtin_bit_cast(float, qq.w << 16);
        o1.w = f2 * __builtin_bit_cast(float, qq.w & 0xffff0000u);
        const int cb = pp * 32 + sub * 8;
        *(float4*)(out + (size_t)gnode * 128 + cb) = o0;
        *(float4*)(out + (size_t)gnode * 128 + cb + 4) = o1;
      }
    }
  }
}

extern "C" void kernel_launch(void* const* d_in, const int* in_sizes, int n_in,
                              void* d_out, int out_size, void* d_ws, size_t ws_size,
                              hipStream_t stream) {
  const float* node = (const float*)d_in[0];        // [N,128] fp32
  const int* adj = (const int*)d_in[1];             // [N,32] int32
  const float* wgt = (const float*)d_in[2];         // [N,32] fp32
  const float* mask = (const float*)d_in[3];        // [N,1] fp32
  const float* mw = (const float*)d_in[4];          // [2,128,128] fp32
  float* out = (float*)d_out;
  const int N = in_sizes[0] / 128;
  const int gb = (N + 63) / 64;
  const int planeBytes = gb * 64 * 64;
  const int nedge = N * 32;

  // d_out scratch: msg1 planes [0,4pB) | scalA — both dead before any out
  // write (out is written only by gather_tail<1>'s tail, which reads ws only).
  unsigned short* msg1 = (unsigned short*)d_out;
  float* scalA = (float*)((char*)d_out + (size_t)4 * planeBytes);
  // ws: wpack 64K | cAB planes 4pB (reused A->B) | msg2 4pB | edges | scalB | flags
  char* ws = (char*)d_ws;
  unsigned short* wpack = (unsigned short*)ws;
  unsigned short* cAB = (unsigned short*)(ws + 65536);
  unsigned short* msg2 = (unsigned short*)(ws + 65536 + (size_t)4 * planeBytes);
  unsigned* edges = (unsigned*)(ws + 65536 + (size_t)8 * planeBytes);
  float* scalB = (float*)(ws + 65536 + (size_t)8 * planeBytes + (size_t)nedge * 4);
  int* flags = (int*)(ws + 65536 + (size_t)8 * planeBytes + (size_t)nedge * 4 +
                      (size_t)N * 32);
  int* flagsA = flags;
  int* flagsB = flags + gb;

  hipLaunchKernelGGL(prep_kernel, dim3((4096 + nedge + 255) / 256), dim3(256), 0,
                     stream, mw, adj, wgt, wpack, edges, flags, nedge, 2 * gb);
  hipLaunchKernelGGL(gemm0_kernel, dim3(gb), dim3(256), 0, stream,
                     node, mask, wpack, msg1, N, planeBytes);
  hipLaunchKernelGGL((gather_tail_kernel<0>), dim3(gb * 4), dim3(256), 0, stream,
                     msg1, edges, cAB, scalA, mask, wpack + 16384, msg2,
                     (float*)nullptr, flagsA, N, planeBytes);
  hipLaunchKernelGGL((gather_tail_kernel<1>), dim3(gb * 4), dim3(256), 0, stream,
                     msg2, edges, cAB, scalB, mask, wpack + 16384,
                     (unsigned short*)nullptr, out, flagsB, N, planeBytes);
}

// Round 10
// 197.616 us; speedup vs baseline: 5.9556x; 5.9556x over previous
//
#include <hip/hip_runtime.h>

#define EPS 1e-5f
#define PROJ_EPS 1e-5f
#define MAX_TANH_ARG 15.0f

typedef __bf16 bf16x8 __attribute__((ext_vector_type(8)));
typedef float f32x4 __attribute__((ext_vector_type(4)));
typedef float f32x2 __attribute__((ext_vector_type(2)));

__device__ __forceinline__ unsigned short f2bf(float f) {
  unsigned u = __builtin_bit_cast(unsigned, f);
  u += 0x7fffu + ((u >> 16) & 1u);   // round-to-nearest-even
  return (unsigned short)(u >> 16);
}

union BF8 {
  unsigned short u[8];
  bf16x8 v;
  uint4 q;
};

// ---------------------------------------------------------------------------
// prep: W[layer][k][n] -> bf16 MFMA B-frag order (W-pack only; edge packing
// lives in gemm0 where it overlaps the MFMA work).
// ---------------------------------------------------------------------------
__global__ __launch_bounds__(256) void prep_kernel(
    const float* __restrict__ W, unsigned short* __restrict__ wpack) {
  const int tid = blockIdx.x * 256 + threadIdx.x;
  if (tid >= 4096) return;
  const int l = tid & 63;
  const int s = (tid >> 6) & 3;
  const int tt = (tid >> 8) & 7;
  const int layer = tid >> 11;
  const int q2 = l >> 4;
  const int n = tt * 16 + (l & 15);
  unsigned short* dst = wpack + ((size_t)((layer * 32 + tt * 4 + s) * 64 + l)) * 8;
  const float* src = W + (size_t)layer * 16384;
#pragma unroll
  for (int j = 0; j < 8; ++j) {
    const int k = s * 32 + q2 * 8 + j;
    dst[j] = f2bf(src[(size_t)k * 128 + n]);
  }
}

// ---------------------------------------------------------------------------
// gemm0: msg1 planes = mask^2 * (node_repr @ W0); also packs this tile's
// edges (u16 id | f16 w) -- coalesced, overlapped with the MFMA pipeline.
// ---------------------------------------------------------------------------
__global__ __launch_bounds__(256) void gemm0_kernel(
    const float* __restrict__ xf, const float* __restrict__ mask,
    const unsigned short* __restrict__ wpack, unsigned short* __restrict__ msg,
    const int* __restrict__ adj, const float* __restrict__ wgt,
    unsigned* __restrict__ edges, int nedge, int N, int planeBytes) {
  __shared__ unsigned short tile[64][136];
  const int t = threadIdx.x;
  const int lane = t & 63;
  const int wv = t >> 6;
  const int m = lane & 15;
  const int quad = lane >> 4;
  const int base = blockIdx.x * 64;
  const int wbase = base + wv * 16;

  // Pack this tile's 2048 edges (8 coalesced iterations).
#pragma unroll
  for (int i = 0; i < 8; ++i) {
    const int ge = base * 32 + i * 256 + t;
    if (ge < nedge) {
      const unsigned id = (unsigned)adj[ge] & 0xffffu;
      const unsigned short h = __builtin_bit_cast(unsigned short, (_Float16)wgt[ge]);
      edges[ge] = id | ((unsigned)h << 16);
    }
  }

  {  // coalesced fp32 load -> bf16 stage into own wave's 16 tile rows
    const int r = lane >> 2;
    const int c = (lane & 3) * 32;
    const int gr = wbase + r;
    const int grc = gr < N ? gr : N - 1;
    const float4* src = (const float4*)(xf + (size_t)grc * 128 + c);
    unsigned short* drow = &tile[wv * 16 + r][c];
#pragma unroll
    for (int i = 0; i < 8; ++i) {
      const float4 p = src[i];
      drow[i * 4 + 0] = f2bf(p.x);
      drow[i * 4 + 1] = f2bf(p.y);
      drow[i * 4 + 2] = f2bf(p.z);
      drow[i * 4 + 3] = f2bf(p.w);
    }
  }

  f32x4 acc[8];
#pragma unroll
  for (int tt = 0; tt < 8; ++tt) acc[tt] = (f32x4){0.f, 0.f, 0.f, 0.f};
#pragma unroll
  for (int sk = 0; sk < 4; ++sk) {
    BF8 a;
    a.q = *(const uint4*)&tile[wv * 16 + m][sk * 32 + quad * 8];
#pragma unroll
    for (int tt = 0; tt < 8; ++tt) {
      BF8 b;
      b.q = *(const uint4*)(wpack + (size_t)((tt * 4 + sk) * 64 + lane) * 8);
      acc[tt] = __builtin_amdgcn_mfma_f32_16x16x32_bf16(a.v, b.v, acc[tt], 0, 0, 0);
    }
  }

  float sc[4];
#pragma unroll
  for (int r = 0; r < 4; ++r) {
    int rr = wbase + quad * 4 + r;
    rr = rr < N ? rr : N - 1;
    const float s = mask[rr];
    sc[r] = s * s;
  }
#pragma unroll
  for (int tt = 0; tt < 8; ++tt) {
    const int c = tt * 16 + m;
#pragma unroll
    for (int r = 0; r < 4; ++r)
      tile[wv * 16 + quad * 4 + r][c] = f2bf(acc[tt][r] * sc[r]);
  }
  const int r16 = lane >> 2;
  const int sub2 = lane & 3;
  const int grow = wbase + r16;
  if (grow < N) {
#pragma unroll
    for (int p = 0; p < 4; ++p) {
      *(uint4*)((char*)msg + (size_t)p * planeBytes + (size_t)grow * 64 + sub2 * 16) =
          *(const uint4*)((const char*)&tile[wv * 16 + r16][0] + p * 64 + sub2 * 16);
    }
  }
}

// ---------------------------------------------------------------------------
// gather_plane: block = (tile = bid>>2, plane p = bid&3); XCD-affine planes.
// 16-deep rolling pipeline: issue 16 uint4 gathers, then consume-k /
// reissue-(k+16), then drain -- ~16 loads in flight per thread throughout.
// __launch_bounds__(256,3) gives the allocator ~168 VGPRs for the q[16] file.
// Epilogue stores relu(c) bf16 plane + per-(node,plane) partials.
// ---------------------------------------------------------------------------
__global__ __launch_bounds__(256, 3) void gather_plane_kernel(
    const unsigned short* __restrict__ msg, const unsigned* __restrict__ edges,
    unsigned short* __restrict__ cout, float* __restrict__ scal,
    int N, int planeBytes) {
  __shared__ unsigned ep[64 * 36];  // stride 36 words: 16B-aligned rows
  const int t = threadIdx.x;
  const int p = blockIdx.x & 3;
  const int nbase = (blockIdx.x >> 2) * 64;

  for (int e = t; e < 64 * 32; e += 256) {
    const int node = e >> 5, k = e & 31;
    const int gn = nbase + node;
    ep[node * 36 + k] = (gn < N) ? edges[(size_t)gn * 32 + k] : 0u;
  }
  __syncthreads();

  const int node = t >> 2;
  const int sub = t & 3;
  const int gnode = nbase + node;
  const unsigned* mp = ep + node * 36;
  const char* plane = (const char*)msg + (size_t)p * planeBytes;
  const int suboff = sub * 16;

  unsigned ew[32];
#pragma unroll
  for (int i = 0; i < 8; ++i)
    *(uint4*)&ew[4 * i] = *(const uint4*)(mp + 4 * i);

  f32x2 acc[4];
#pragma unroll
  for (int d = 0; d < 4; ++d) acc[d] = (f32x2){0.f, 0.f};

  uint4 q[16];
#pragma unroll
  for (int k = 0; k < 16; ++k)
    q[k] = *(const uint4*)(plane + ((size_t)(ew[k] & 0xffffu) * 64 + suboff));

  // consume k, immediately reissue slot k for edge k+16
#pragma unroll
  for (int k = 0; k < 16; ++k) {
    const float w = (float)__builtin_bit_cast(_Float16, (unsigned short)(ew[k] >> 16));
    const f32x2 w2 = {w, w};
    const uint4 qq = q[k];
    q[k] = *(const uint4*)(plane + ((size_t)(ew[16 + k] & 0xffffu) * 64 + suboff));
#pragma unroll
    for (int d = 0; d < 4; ++d) {
      const unsigned qd = (&qq.x)[d];
      f32x2 v2;
      v2.x = __builtin_bit_cast(float, qd << 16);
      v2.y = __builtin_bit_cast(float, qd & 0xffff0000u);
      acc[d] = __builtin_elementwise_fma(v2, w2, acc[d]);
    }
  }
  // drain
#pragma unroll
  for (int k = 0; k < 16; ++k) {
    const float w = (float)__builtin_bit_cast(_Float16,
                                              (unsigned short)(ew[16 + k] >> 16));
    const f32x2 w2 = {w, w};
#pragma unroll
    for (int d = 0; d < 4; ++d) {
      const unsigned qd = (&q[k].x)[d];
      f32x2 v2;
      v2.x = __builtin_bit_cast(float, qd << 16);
      v2.y = __builtin_bit_cast(float, qd & 0xffff0000u);
      acc[d] = __builtin_elementwise_fma(v2, w2, acc[d]);
    }
  }

  float s_all = 0.f, s_rel = 0.f;
  uint4 pk4;
  unsigned* pw = &pk4.x;
#pragma unroll
  for (int d = 0; d < 4; ++d) {
    s_all = fmaf(acc[d].x, acc[d].x, s_all);
    s_all = fmaf(acc[d].y, acc[d].y, s_all);
    const float r0 = fmaxf(acc[d].x, 0.f);
    const float r1 = fmaxf(acc[d].y, 0.f);
    s_rel = fmaf(r0, r0, s_rel);
    s_rel = fmaf(r1, r1, s_rel);
    pw[d] = (unsigned)f2bf(r0) | ((unsigned)f2bf(r1) << 16);
  }
  s_all += __shfl_xor(s_all, 1);
  s_all += __shfl_xor(s_all, 2);
  s_rel += __shfl_xor(s_rel, 1);
  s_rel += __shfl_xor(s_rel, 2);

  if (gnode < N) {
    *(uint4*)((char*)cout + (size_t)p * planeBytes + (size_t)gnode * 64 + suboff) = pk4;
    if (sub == 0)
      *(float2*)(scal + (size_t)gnode * 8 + p * 2) = make_float2(s_all, s_rel);
  }
}

// ---------------------------------------------------------------------------
// gemm1: msg2 planes = rs * (relu(c1) @ W1), rs = ls*mm^2*f1 computed inline
// from the per-plane partials (f1 = esc*mm^3; x1 = f1*relu(c1)).
// ---------------------------------------------------------------------------
__global__ __launch_bounds__(256) void gemm1_kernel(
    const unsigned short* __restrict__ cA, const float* __restrict__ scalA,
    const float* __restrict__ mask, const unsigned short* __restrict__ wpack2,
    unsigned short* __restrict__ msg, int N, int planeBytes) {
  __shared__ unsigned short tile[64][136];
  const int lane = threadIdx.x & 63;
  const int wv = threadIdx.x >> 6;
  const int m = lane & 15;
  const int quad = lane >> 4;
  const int wbase = blockIdx.x * 64 + wv * 16;
  const int row = wbase + m;
  const int rowc = row < N ? row : N - 1;

  f32x4 acc[8];
#pragma unroll
  for (int tt = 0; tt < 8; ++tt) acc[tt] = (f32x4){0.f, 0.f, 0.f, 0.f};
#pragma unroll
  for (int sk = 0; sk < 4; ++sk) {
    BF8 a;
    a.q = *(const uint4*)((const char*)cA + (size_t)sk * planeBytes +
                          (size_t)rowc * 64 + quad * 16);
#pragma unroll
    for (int tt = 0; tt < 8; ++tt) {
      BF8 b;
      b.q = *(const uint4*)(wpack2 + (size_t)((tt * 4 + sk) * 64 + lane) * 8);
      acc[tt] = __builtin_amdgcn_mfma_f32_16x16x32_bf16(a.v, b.v, acc[tt], 0, 0, 0);
    }
  }

  float sc[4];
#pragma unroll
  for (int r = 0; r < 4; ++r) {
    int rr = wbase + quad * 4 + r;
    rr = rr < N ? rr : N - 1;
    const float* s8 = scalA + (size_t)rr * 8;
    const float S_all = s8[0] + s8[2] + s8[4] + s8[6];
    const float S_rel = s8[1] + s8[3] + s8[5] + s8[7];
    const float mm = mask[rr];
    const float s2 = mm * mm * S_all;
    const float nrm = sqrtf(s2);
    const float ncl = fminf(fmaxf(nrm, EPS), MAX_TANH_ARG);
    const float f1 = tanhf(ncl) / fmaxf(nrm, EPS) * mm * mm * mm;  // x1 = f1*relu(c1)
    const float r2 = f1 * f1 * S_rel;
    const float nr = sqrtf(r2);
    const float nc2 = fminf(fmaxf(nr, EPS), 1.0f - PROJ_EPS);
    const float ls = 0.5f * logf((1.f + nc2) / (1.f - nc2)) / fmaxf(nr, EPS);
    sc[r] = ls * mm * mm * f1;
  }
#pragma unroll
  for (int tt = 0; tt < 8; ++tt) {
    const int c = tt * 16 + m;
#pragma unroll
    for (int r = 0; r < 4; ++r)
      tile[wv * 16 + quad * 4 + r][c] = f2bf(acc[tt][r] * sc[r]);
  }
  const int r16 = lane >> 2;
  const int sub2 = lane & 3;
  const int grow = wbase + r16;
  if (grow < N) {
#pragma unroll
    for (int p = 0; p < 4; ++p) {
      *(uint4*)((char*)msg + (size_t)p * planeBytes + (size_t)grow * 64 + sub2 * 16) =
          *(const uint4*)((const char*)&tile[wv * 16 + r16][0] + p * 64 + sub2 * 16);
    }
  }
}

// ---------------------------------------------------------------------------
// final: out = f2 * relu(c2), f2 = tanh(clip(|c2*m|))/|..| * m^3, fp32 stores.
// ---------------------------------------------------------------------------
__global__ __launch_bounds__(256) void final_kernel(
    const unsigned short* __restrict__ cB, const float* __restrict__ scalB,
    const float* __restrict__ mask, float* __restrict__ out,
    int N, int planeBytes) {
  const int t = threadIdx.x;
  const int node = t >> 2;
  const int sub = t & 3;
  const int gnode = blockIdx.x * 64 + node;
  if (gnode >= N) return;
  const float* s8 = scalB + (size_t)gnode * 8;
  const float S_all = s8[0] + s8[2] + s8[4] + s8[6];
  const float mm = mask[gnode];
  const float s2 = mm * mm * S_all;
  const float nrm = sqrtf(s2);
  const float ncl = fminf(fmaxf(nrm, EPS), MAX_TANH_ARG);
  const float f2 = tanhf(ncl) / fmaxf(nrm, EPS) * mm * mm * mm;
#pragma unroll
  for (int p = 0; p < 4; ++p) {
    const uint4 q = *(const uint4*)((const char*)cB + (size_t)p * planeBytes +
                                    (size_t)gnode * 64 + sub * 16);
    float4 o0, o1;
    o0.x = f2 * __builtin_bit_cast(float, q.x << 16);
    o0.y = f2 * __builtin_bit_cast(float, q.x & 0xffff0000u);
    o0.z = f2 * __builtin_bit_cast(float, q.y << 16);
    o0.w = f2 * __builtin_bit_cast(float, q.y & 0xffff0000u);
    o1.x = f2 * __builtin_bit_cast(float, q.z << 16);
    o1.y = f2 * __builtin_bit_cast(float, q.z & 0xffff0000u);
    o1.z = f2 * __builtin_bit_cast(float, q.w << 16);
    o1.w = f2 * __builtin_bit_cast(float, q.w & 0xffff0000u);
    const int cb = p * 32 + sub * 8;
    *(float4*)(out + (size_t)gnode * 128 + cb) = o0;
    *(float4*)(out + (size_t)gnode * 128 + cb + 4) = o1;
  }
}

extern "C" void kernel_launch(void* const* d_in, const int* in_sizes, int n_in,
                              void* d_out, int out_size, void* d_ws, size_t ws_size,
                              hipStream_t stream) {
  const float* node = (const float*)d_in[0];        // [N,128] fp32
  const int* adj = (const int*)d_in[1];             // [N,32] int32
  const float* wgt = (const float*)d_in[2];         // [N,32] fp32
  const float* mask = (const float*)d_in[3];        // [N,1] fp32
  const float* mw = (const float*)d_in[4];          // [2,128,128] fp32
  float* out = (float*)d_out;
  const int N = in_sizes[0] / 128;
  const int gb = (N + 63) / 64;
  const int planeBytes = gb * 64 * 64;
  const int nedge = N * 32;

  // d_out scratch: [0,4*pB) msg planes (msg1 then msg2) | edges (4B*nedge) |
  //                scalarsA (N*32 B). All dead before final_kernel's writes.
  unsigned short* msg = (unsigned short*)d_out;
  unsigned* edges = (unsigned*)((char*)d_out + (size_t)4 * planeBytes);
  float* scalA = (float*)((char*)d_out + (size_t)4 * planeBytes + (size_t)nedge * 4);
  // ws: wpack 64 KiB | cA/cB planes (4*pB, reused) | scalarsB (N*32 B)
  unsigned short* wpack = (unsigned short*)d_ws;
  unsigned short* cAB = (unsigned short*)((char*)d_ws + 65536);
  float* scalB = (float*)((char*)d_ws + 65536 + (size_t)4 * planeBytes);

  hipLaunchKernelGGL(prep_kernel, dim3(16), dim3(256), 0, stream, mw, wpack);
  hipLaunchKernelGGL(gemm0_kernel, dim3(gb), dim3(256), 0, stream,
                     node, mask, wpack, msg, adj, wgt, edges, nedge, N, planeBytes);
  hipLaunchKernelGGL(gather_plane_kernel, dim3(gb * 4), dim3(256), 0, stream,
                     msg, edges, cAB, scalA, N, planeBytes);
  hipLaunchKernelGGL(gemm1_kernel, dim3(gb), dim3(256), 0, stream,
                     cAB, scalA, mask, wpack + 16384, msg, N, planeBytes);
  hipLaunchKernelGGL(gather_plane_kernel, dim3(gb * 4), dim3(256), 0, stream,
                     msg, edges, cAB, scalB, N, planeBytes);
  hipLaunchKernelGGL(final_kernel, dim3(gb), dim3(256), 0, stream,
                     cAB, scalB, mask, out, N, planeBytes);
}